// Round 14
// baseline (28.279 us; speedup 1.0000x reference)
//
#include <hip/hip_runtime.h>

#define B 8
#define K 8
#define H 384
#define W 384
#define HW (H*W)                 // 147456 pixels per batch
#define NCPP 16                  // chunks per (b,k) plane in stage A
#define GROUPS_PER_B (HW/4)      // 36864 float4-groups per batch

typedef float f32x4 __attribute__((ext_vector_type(4)));

__device__ __forceinline__ float4 ntload4(const float* p) {
    f32x4 v = __builtin_nontemporal_load((const f32x4*)p);
    return make_float4(v.x, v.y, v.z, v.w);
}

// ws layout (floats): [0, B*K*NCPP*4) stage-A partials,
//   ws[((b*K+k)*NCPP + ch)*4 + comp], comp = {sum_m, sum_mdx, sum_mdy, sum_md}

__device__ __forceinline__ void euler2mat(float ax, float ay, float az, float R[9]) {
    float cx = cosf(ax), sx = sinf(ax);
    float cy = cosf(ay), sy = sinf(ay);
    float cz = cosf(az), sz = sinf(az);
    // R = xmat @ ymat @ zmat
    R[0] = cy*cz;              R[1] = -cy*sz;             R[2] = sy;
    R[3] = cx*sz + sx*sy*cz;   R[4] = cx*cz - sx*sy*sz;   R[5] = -sx*cy;
    R[6] = sx*sz - cx*sy*cz;   R[7] = sx*cz + cx*sy*sz;   R[8] = cx*cy;
}

// ---------------- Stage A: byte-identical to round 10 (measured ~7 us, at roofline) ----------------
__global__ __launch_bounds__(256) void k_reduce(const float* __restrict__ mask,
                                                const float* __restrict__ depth,
                                                float* __restrict__ ws) {
    const int chunk = blockIdx.x, k = blockIdx.y, b = blockIdx.z;
    const int tid = threadIdx.x;

    const float* mbase = mask + ((size_t)(b*K + k)) * HW;
    const float4* d4 = (const float4*)(depth + (size_t)b * HW);

    float s0 = 0.f, s1 = 0.f, s2 = 0.f, s3 = 0.f;
    const float inv = 2.f / W;

#pragma unroll
    for (int r = 0; r < 9; ++r) {
        int g = (chunk * 9 + r) * 256 + tid;   // float4-group in [0, 36864)
        float4 mv = ntload4(mbase + (size_t)g * 4);
        float4 dv = d4[g];
        int i0 = g * 4;
        int h = i0 / W;
        int w0 = i0 - h * W;                   // 4 | W: all 4 pixels share row h
        float py = 2.f * (h + 0.5f) * (1.f / H) - 1.f;
        float px0 = 2.f * (w0 + 0.5f) * (1.f / W) - 1.f;
        float mm[4] = {mv.x, mv.y, mv.z, mv.w};
        float dd[4] = {dv.x, dv.y, dv.z, dv.w};
#pragma unroll
        for (int j = 0; j < 4; ++j) {
            float m = mm[j];
            float t = m * dd[j];
            float px = px0 + j * inv;
            s0 += m; s1 += t * px; s2 += t * py; s3 += t;
        }
    }

    for (int off = 32; off > 0; off >>= 1) {
        s0 += __shfl_down(s0, off);
        s1 += __shfl_down(s1, off);
        s2 += __shfl_down(s2, off);
        s3 += __shfl_down(s3, off);
    }
    __shared__ float sd[16];
    int lane = tid & 63, wid = tid >> 6;
    if (lane == 0) { sd[wid*4+0]=s0; sd[wid*4+1]=s1; sd[wid*4+2]=s2; sd[wid*4+3]=s3; }
    __syncthreads();
    if (tid < 4) {
        float v = sd[tid] + sd[4 + tid] + sd[8 + tid] + sd[12 + tid];
        ws[(((b*K + k) * NCPP) + chunk) * 4 + tid] = v;
    }
}

// ---------------- Stage B+C: LONG-RUN plane-sequential flow ----------------
// Footprint change vs R10/R13: each block owns 512 CONTIGUOUS groups (8 KB per
// plane, like k_reduce's long runs) instead of a 4 KB window; planes processed
// sequentially (k-sum separable), depth-2 plane prefetch keeps 2 loads in
// flight inside one plane's window. Per-accumulator add order (k ascending)
// unchanged -> bit-exact with all passing rounds.
__global__ __launch_bounds__(256) void k_flow(const float* __restrict__ mask,
                                              const float* __restrict__ depth,
                                              const float* __restrict__ T,
                                              const float* __restrict__ Tc,
                                              const float* __restrict__ ws,
                                              float* __restrict__ out) {
    const int b = blockIdx.y;
    const int tid = threadIdx.x;

    __shared__ float sP[512];
    __shared__ float s32[32];
    __shared__ float sp[108];

    const int gA = blockIdx.x * 512 + tid;        // first quad-group
    const int gB = gA + 256;                      // second quad-group
    const float* mbase = mask + ((size_t)b * K) * HW;

    // issue depth + plane-0 prefetch first
    float4 dvA = ((const float4*)(depth + (size_t)b * HW))[gA];
    float4 dvB = ((const float4*)(depth + (size_t)b * HW))[gB];
    float4 curA = ntload4(mbase + (size_t)gA * 4);
    float4 curB = ntload4(mbase + (size_t)gB * 4);

    // ---- stage partials to LDS (coalesced) ----
    if (tid < 128)
        ((float4*)sP)[tid] = ((const float4*)(ws + (size_t)b * 512))[tid];
    __syncthreads();

    // ---- fold (same add order as round 2) ----
    if (tid < 32) {
        int k = tid >> 2, comp = tid & 3;
        float s = 0.f;
#pragma unroll
        for (int ch = 0; ch < NCPP; ++ch) s += sP[(k * NCPP + ch) * 4 + comp];
        s32[tid] = s;
    }
    __syncthreads();

    if (tid < 8) {
        int k = tid;
        float mass = s32[k*4 + 0] + 1e-6f;
        float p0 = s32[k*4 + 1] / mass;
        float p1 = s32[k*4 + 2] / mass;
        float p2 = s32[k*4 + 3] / mass;
        const float* Tk = T + (b*K + k) * 6;
        float R[9];
        euler2mat(Tk[3], Tk[4], Tk[5], R);
        float Rp0 = R[0]*p0 + R[1]*p1 + R[2]*p2;
        float Rp1 = R[3]*p0 + R[4]*p1 + R[5]*p2;
        float Rp2 = R[6]*p0 + R[7]*p1 + R[8]*p2;
        float* o = sp + k * 12;
        o[0] = R[0] - 1.f; o[1] = R[1];       o[2] = R[2];
        o[3] = R[3];       o[4] = R[4] - 1.f; o[5] = R[5];
        o[6] = R[6];       o[7] = R[7];       o[8] = R[8] - 1.f;
        o[9]  = p0 + Tk[0] - Rp0;
        o[10] = p1 + Tk[1] - Rp1;
        o[11] = p2 + Tk[2] - Rp2;
    } else if (tid == 8) {
        const float* Tb = Tc + b * 9;
        float R[9];
        euler2mat(Tb[3], Tb[4], Tb[5], R);
        float pc0 = Tb[6], pc1 = Tb[7], pc2 = Tb[8];
        float* o = sp + 96;
#pragma unroll
        for (int i = 0; i < 9; ++i) o[i] = R[i];
        o[9]  = pc0 + Tb[0] - (R[0]*pc0 + R[1]*pc1 + R[2]*pc2);
        o[10] = pc1 + Tb[1] - (R[3]*pc0 + R[4]*pc1 + R[5]*pc2);
        o[11] = pc2 + Tb[2] - (R[6]*pc0 + R[7]*pc1 + R[8]*pc2);
    }
    __syncthreads();

    // ---- pixel constants for both quads ----
    const float inv = 2.f / W;
    int hA = gA / 96, hB = gB / 96;
    float pyA = 2.f * (hA + 0.5f) * (1.f / H) - 1.f;
    float pyB = 2.f * (hB + 0.5f) * (1.f / H) - 1.f;
    float pxA0 = 2.f * ((gA - hA*96)*4 + 0.5f) * (1.f / W) - 1.f;
    float pxB0 = 2.f * ((gB - hB*96)*4 + 0.5f) * (1.f / W) - 1.f;

    float ddA[4] = {dvA.x, dvA.y, dvA.z, dvA.w};
    float ddB[4] = {dvB.x, dvB.y, dvB.z, dvB.w};
    float pxjA[4], pxjB[4];
    float wxA[4], wyA[4], wzA[4], axA[4], ayA[4], azA[4];
    float wxB[4], wyB[4], wzB[4], axB[4], ayB[4], azB[4];
#pragma unroll
    for (int j = 0; j < 4; ++j) {
        pxjA[j] = pxA0 + j * inv;
        pxjB[j] = pxB0 + j * inv;
        wxA[j] = ddA[j] * pxjA[j]; wyA[j] = ddA[j] * pyA; wzA[j] = ddA[j];
        wxB[j] = ddB[j] * pxjB[j]; wyB[j] = ddB[j] * pyB; wzB[j] = ddB[j];
        axA[j] = wxA[j]; ayA[j] = wyA[j]; azA[j] = wzA[j];
        axB[j] = wxB[j]; ayB[j] = wyB[j]; azB[j] = wzB[j];
    }

    // ---- plane-sequential accumulation over the block's 8 KB run ----
#pragma unroll
    for (int k = 0; k < K; ++k) {
        float4 nxtA = curA, nxtB = curB;
        if (k < K - 1) {
            nxtA = ntload4(mbase + (size_t)(k + 1) * HW + (size_t)gA * 4);
            nxtB = ntload4(mbase + (size_t)(k + 1) * HW + (size_t)gB * 4);
        }
        const float* P = sp + k * 12;
        float mA[4] = {curA.x, curA.y, curA.z, curA.w};
        float mB[4] = {curB.x, curB.y, curB.z, curB.w};
#pragma unroll
        for (int j = 0; j < 4; ++j) {
            float rx = P[0]*wxA[j] + P[1]*wyA[j] + P[2]*wzA[j] + P[9];
            float ry = P[3]*wxA[j] + P[4]*wyA[j] + P[5]*wzA[j] + P[10];
            float rz = P[6]*wxA[j] + P[7]*wyA[j] + P[8]*wzA[j] + P[11];
            axA[j] += mA[j] * rx; ayA[j] += mA[j] * ry; azA[j] += mA[j] * rz;
            float sx2 = P[0]*wxB[j] + P[1]*wyB[j] + P[2]*wzB[j] + P[9];
            float sy2 = P[3]*wxB[j] + P[4]*wyB[j] + P[5]*wzB[j] + P[10];
            float sz2 = P[6]*wxB[j] + P[7]*wyB[j] + P[8]*wzB[j] + P[11];
            axB[j] += mB[j] * sx2; ayB[j] += mB[j] * sy2; azB[j] += mB[j] * sz2;
        }
        __builtin_amdgcn_sched_barrier(0);    // keep plane order; no load hoisting
        curA = nxtA; curB = nxtB;
    }

    // ---- camera transform + divide, store both quads ----
    const float* C = sp + 96;
    float resA[8], resB[8];
#pragma unroll
    for (int j = 0; j < 4; ++j) {
        float ox = C[0]*axA[j] + C[1]*ayA[j] + C[2]*azA[j] + C[9];
        float oy = C[3]*axA[j] + C[4]*ayA[j] + C[5]*azA[j] + C[10];
        float oz = C[6]*axA[j] + C[7]*ayA[j] + C[8]*azA[j] + C[11];
        resA[j*2+0] = ox / oz - pxjA[j];
        resA[j*2+1] = oy / oz - pyA;
        float ox2 = C[0]*axB[j] + C[1]*ayB[j] + C[2]*azB[j] + C[9];
        float oy2 = C[3]*axB[j] + C[4]*ayB[j] + C[5]*azB[j] + C[10];
        float oz2 = C[6]*axB[j] + C[7]*ayB[j] + C[8]*azB[j] + C[11];
        resB[j*2+0] = ox2 / oz2 - pxjB[j];
        resB[j*2+1] = oy2 / oz2 - pyB;
    }

    f32x4* oA = (f32x4*)(out + ((size_t)b * HW + (size_t)gA * 4) * 2);
    f32x4 vA0 = {resA[0], resA[1], resA[2], resA[3]};
    f32x4 vA1 = {resA[4], resA[5], resA[6], resA[7]};
    __builtin_nontemporal_store(vA0, oA);
    __builtin_nontemporal_store(vA1, oA + 1);
    f32x4* oB = (f32x4*)(out + ((size_t)b * HW + (size_t)gB * 4) * 2);
    f32x4 vB0 = {resB[0], resB[1], resB[2], resB[3]};
    f32x4 vB1 = {resB[4], resB[5], resB[6], resB[7]};
    __builtin_nontemporal_store(vB0, oB);
    __builtin_nontemporal_store(vB1, oB + 1);
}

extern "C" void kernel_launch(void* const* d_in, const int* in_sizes, int n_in,
                              void* d_out, int out_size, void* d_ws, size_t ws_size,
                              hipStream_t stream) {
    // inputs: im (unused), mask, depth, T, Tc — all float32
    const float* mask  = (const float*)d_in[1];
    const float* depth = (const float*)d_in[2];
    const float* T     = (const float*)d_in[3];
    const float* Tc    = (const float*)d_in[4];
    float* ws  = (float*)d_ws;
    float* out = (float*)d_out;

    k_reduce<<<dim3(NCPP, K, B), 256, 0, stream>>>(mask, depth, ws);
    k_flow<<<dim3(GROUPS_PER_B / 512, B), 256, 0, stream>>>(mask, depth, T, Tc, ws, out);
}